// Round 20
// baseline (189.993 us; speedup 1.0000x reference)
//
#include <hip/hip_runtime.h>

#define NN 50000
#define EE 800000
#define CAP 32          // u16 slots/node -> 3.2 MB csrf
#define OVF_CAP 4096
#define LOG2E 1.44269504088896340736f
#define NWG 2346        // 6 col-panels * 391 row-tiles
#define XQ 293          // NWG/8
#define XR 2            // NWG%8
#define SCAT_BLK 782    // ceil(200000/256); 4 edges/thread

typedef __attribute__((ext_vector_type(4))) float f32x4;
typedef __attribute__((ext_vector_type(2))) float f32x2;
typedef __attribute__((ext_vector_type(8))) short bf16x8;
typedef unsigned int u32;
typedef unsigned short u16;
#define GLOBAL_AS __attribute__((address_space(1)))
#define LDS_AS __attribute__((address_space(3)))

static __device__ __forceinline__ u32 cvtpk_bf16(float lo, float hi) {
  u32 r;
  asm("v_cvt_pk_bf16_f32 %0, %1, %2" : "=v"(r) : "v"(lo), "v"(hi));
  return r;
}
static __device__ __forceinline__ u16 f2bf_hw(float f) {
  return (u16)cvtpk_bf16(f, 0.f);
}
static __device__ __forceinline__ float bfl(unsigned int u) { return __uint_as_float(u << 16); }
static __device__ __forceinline__ float bfh(unsigned int u) { return __uint_as_float(u & 0xFFFF0000u); }

// ---- fused prep (R17 proven): SCATTER FIRST, then conv x | conv W | att ----
__global__ void k_prep(const float4* __restrict__ x4,
                       const float4* __restrict__ Wl, const float4* __restrict__ Wr,
                       const float4* __restrict__ Ws, const float* __restrict__ att,
                       const int* __restrict__ ei,
                       uint2* __restrict__ xb2, uint2* __restrict__ wb2,
                       float* __restrict__ av6, float* __restrict__ av04,
                       int* __restrict__ cnt, u16* __restrict__ csrf,
                       int* __restrict__ ovf) {
  int b = blockIdx.x;
  if (b < SCAT_BLK) {
    int t = b * 256 + threadIdx.x;
    if (t < EE / 4) {
#pragma unroll
      for (int u = 0; u < 4; ++u) {
        int e = t + u * (EE / 4);
        int dst = ei[EE + e];
        int src = ei[e];
        int slot = atomicAdd(&cnt[dst], 1);
        if (slot < CAP) {
          csrf[dst * CAP + slot] = (u16)src;
        } else {  // guaranteed-correct fallback (~15 edges for Poisson(16))
          int o = atomicAdd(&cnt[NN], 1);  // cnt[NN] = overflow counter
          if (o < OVF_CAP) { ovf[2 * o] = dst; ovf[2 * o + 1] = src; }
        }
      }
    }
  } else if (b < SCAT_BLK + 12500) {
    int i = (b - SCAT_BLK) * 256 + threadIdx.x;  // < 3200000 exactly
    float4 v = x4[i];
    uint2 o;
    o.x = cvtpk_bf16(v.x, v.y);
    o.y = cvtpk_bf16(v.z, v.w);
    xb2[i] = o;
  } else if (b < SCAT_BLK + 12692) {
    int i = (b - SCAT_BLK - 12500) * 256 + threadIdx.x;  // over 49152
    if (i < 49152) {
      int which = i >> 14;
      int idx = i & 16383;
      const float4* W = (which == 0) ? Wl : (which == 1) ? Wr : Ws;
      float4 v = W[idx];
      uint2 o;
      o.x = cvtpk_bf16(v.x, v.y);
      o.y = cvtpk_bf16(v.z, v.w);
      wb2[i] = o;
    }
  } else {
    float a = att[threadIdx.x];
    av6[threadIdx.x] = 0.6f * LOG2E * a;
    av04[threadIdx.x] = 0.4f * LOG2E * a;
  }
}

// ---- GEMM (R10 proven): 32 KB 2-barrier loop, XCD-bijective swizzle,
// LDS-transposed coalesced epilogue, bf16 outputs.
__global__ __launch_bounds__(256) void k_gemm(const unsigned short* __restrict__ xb,
                                              const unsigned short* __restrict__ wb,
                                              unsigned short* __restrict__ xlb,
                                              unsigned short* __restrict__ zb) {
  __shared__ alignas(16) unsigned short Sm[2][128 * 64];
  const int tid = threadIdx.x;
  const int lane = tid & 63;
  const int wave = tid >> 6;
  const int wr = wave >> 1, wc = wave & 1;
  // bijective XCD swizzle (m204): contiguous logical chunk per XCD
  int bid = blockIdx.x;
  int xcd = bid & 7, slot = bid >> 3;
  int wgid = (xcd < XR ? xcd * (XQ + 1) : XR * (XQ + 1) + (xcd - XR) * XQ) + slot;
  const int rbase = (wgid / 6) * 128;
  const int cbase = (wgid % 6) * 128;
  const int rl = lane & 15;
  const int q = lane >> 4;

  f32x4 acc[4][4];
#pragma unroll
  for (int a = 0; a < 4; ++a)
#pragma unroll
    for (int b = 0; b < 4; ++b) acc[a][b] = (f32x4){0.f, 0.f, 0.f, 0.f};

  for (int kt = 0; kt < 256; kt += 64) {
#pragma unroll
    for (int i = 0; i < 4; ++i) {
      int c = tid + i * 256;            // chunk id: 1024 chunks of 16B per buffer
      int row = c >> 3, kcx = c & 7;    // kcx = physical (linear LDS) slot
      int kc = kcx ^ (row & 7);         // logical k-chunk living in slot kcx
      int gr = rbase + row; if (gr > NN - 1) gr = NN - 1;
      int ldsoff = i * 4096 + wave * 1024;  // wave-uniform byte base
      __builtin_amdgcn_global_load_lds(
          (const GLOBAL_AS u32*)(xb + (size_t)gr * 256 + kt + kc * 8),
          (LDS_AS u32*)((LDS_AS char*)&Sm[0][0] + ldsoff), 16, 0, 0);
      __builtin_amdgcn_global_load_lds(
          (const GLOBAL_AS u32*)(wb + (size_t)(cbase + row) * 256 + kt + kc * 8),
          (LDS_AS u32*)((LDS_AS char*)&Sm[1][0] + ldsoff), 16, 0, 0);
    }
    __syncthreads();
#pragma unroll
    for (int ks = 0; ks < 2; ++ks) {
      bf16x8 af[4], bf[4];
      int kc = ks * 4 + q;
#pragma unroll
      for (int t = 0; t < 4; ++t) {
        int ra = wr * 64 + t * 16 + rl;
        af[t] = *(const bf16x8*)((const char*)&Sm[0][0] + ra * 128 + ((kc << 4) ^ ((ra & 7) << 4)));
        int rb = wc * 64 + t * 16 + rl;
        bf[t] = *(const bf16x8*)((const char*)&Sm[1][0] + rb * 128 + ((kc << 4) ^ ((rb & 7) << 4)));
      }
#pragma unroll
      for (int a = 0; a < 4; ++a)
#pragma unroll
        for (int b = 0; b < 4; ++b)
          acc[a][b] = __builtin_amdgcn_mfma_f32_16x16x32_bf16(af[a], bf[b], acc[a][b], 0, 0, 0);
    }
    __syncthreads();
  }
  // ---- epilogue: stage C tile in LDS (swizzled), then coalesced 16B stores ----
  char* Cs = (char*)&Sm[0][0];  // 32 KB = [128 rows][128 cols] bf16, XOR-swizzled
#pragma unroll
  for (int a = 0; a < 4; ++a) {
#pragma unroll
    for (int j = 0; j < 4; ++j) {
      int row = wr * 64 + a * 16 + q * 4 + j;
      int tag = ((row >> 2) & 7) << 5;
#pragma unroll
      for (int b = 0; b < 4; ++b) {
        int col = wc * 64 + b * 16 + rl;
        *(unsigned short*)(Cs + row * 256 + ((col * 2) ^ tag)) = f2bf_hw(acc[a][b][j]);
      }
    }
  }
  __syncthreads();
  const bool isxl = (cbase < 256);
  unsigned short* dst = isxl ? (xlb + cbase) : (zb + (cbase - 256));
  const int dstride = isxl ? 256 : 512;
#pragma unroll
  for (int it = 0; it < 8; ++it) {
    int id = it * 256 + tid;
    int row = id >> 4, cch = id & 15;   // 16 chunks of 8 cols per row
    int tag = ((row >> 2) & 7) << 5;
    uint4 v = *(const uint4*)(Cs + row * 256 + ((cch * 16) ^ tag));
    int grow = rbase + row;
    if (grow < NN)
      *(uint4*)(dst + (size_t)grow * dstride + cch * 8) = v;
  }
}

// ---- per-node FLAT-softmax aggregation (packed-FP32 VOP3P math) ----
// Channel math on f32x2 pairs: pk_add/pk_max(neg free)/pk_fma halve the
// per-edge VALU issue count; two packed accumulator sets keep the A/B
// dependence split. Worst case (compiler scalarizes) == R17 code.
#define PLOGIT(e01, e23, p)                                            \
  {                                                                    \
    f32x2 t01 = e01 + xr01, t23 = e23 + xr23;                          \
    f32x2 q2 = a6_01 * t01 + a04_01 * __builtin_elementwise_max(t01, -t01); \
    q2 = q2 + a6_23 * t23 + a04_23 * __builtin_elementwise_max(t23, -t23);  \
    p = q2.x + q2.y;                                                   \
  }

#define EDGE1(sidx)                                                    \
  {                                                                    \
    uint2 v0 = xl2[(u32)(sidx) * 64u + (u32)lane];                     \
    f32x2 e01 = {bfl(v0.x), bfh(v0.x)};                                \
    f32x2 e23 = {bfl(v0.y), bfh(v0.y)};                                \
    float p0;                                                          \
    PLOGIT(e01, e23, p0)                                               \
    p0 += __shfl_xor(p0, 1);                                           \
    p0 += __shfl_xor(p0, 2);                                           \
    p0 += __shfl_xor(p0, 4);                                           \
    p0 = exp2f(p0);                                                    \
    f32x2 pp = {p0, p0};                                               \
    sA += p0; a01A = a01A + pp * e01; a23A = a23A + pp * e23;          \
  }

__global__ __launch_bounds__(256) void k_agg(const uint2* __restrict__ xl2,
                                             const uint2* __restrict__ zb2,
                                             const int* __restrict__ cnt,
                                             const u16* __restrict__ csrf,
                                             const int* __restrict__ ovf,
                                             const float* __restrict__ av6,
                                             const float* __restrict__ av04,
                                             const float* __restrict__ bias,
                                             float* __restrict__ out) {
  int node = blockIdx.x * 4 + (threadIdx.x >> 6);
  if (node >= NN) return;
  int lane = threadIdx.x & 63;

  uint2 xrv = zb2[(u32)node * 128u + (u32)lane];
  const f32x2 xr01 = {bfl(xrv.x), bfh(xrv.x)};
  const f32x2 xr23 = {bfl(xrv.y), bfh(xrv.y)};
  const f32x2 a6_01 = *(const f32x2*)(av6 + lane * 4);
  const f32x2 a6_23 = *(const f32x2*)(av6 + lane * 4 + 2);
  const f32x2 a04_01 = *(const f32x2*)(av04 + lane * 4);
  const f32x2 a04_23 = *(const f32x2*)(av04 + lane * 4 + 2);

  float sA = 0.f, sB = 0.f;
  f32x2 a01A = {0.f, 0.f}, a23A = {0.f, 0.f};
  f32x2 a01B = {0.f, 0.f}, a23B = {0.f, 0.f};

  EDGE1(node)  // self-loop

  int nedge = cnt[node];
  if (nedge > CAP) nedge = CAP;
  const u32 base = (u32)node * CAP;
  int i = 0;
  for (; i + 4 <= nedge; i += 4) {
    ushort4 sv = *(const ushort4*)(csrf + base + (u32)i);  // 8B-aligned
    uint2 v0 = xl2[(u32)sv.x * 64u + (u32)lane];
    uint2 v1 = xl2[(u32)sv.y * 64u + (u32)lane];
    uint2 v2 = xl2[(u32)sv.z * 64u + (u32)lane];
    uint2 v3 = xl2[(u32)sv.w * 64u + (u32)lane];
    f32x2 e0a = {bfl(v0.x), bfh(v0.x)}, e0b = {bfl(v0.y), bfh(v0.y)};
    f32x2 e1a = {bfl(v1.x), bfh(v1.x)}, e1b = {bfl(v1.y), bfh(v1.y)};
    f32x2 e2a = {bfl(v2.x), bfh(v2.x)}, e2b = {bfl(v2.y), bfh(v2.y)};
    f32x2 e3a = {bfl(v3.x), bfh(v3.x)}, e3b = {bfl(v3.y), bfh(v3.y)};
    float p0, p1, p2, p3;
    PLOGIT(e0a, e0b, p0)
    PLOGIT(e1a, e1b, p1)
    PLOGIT(e2a, e2b, p2)
    PLOGIT(e3a, e3b, p3)
    p0 += __shfl_xor(p0, 1); p1 += __shfl_xor(p1, 1);
    p2 += __shfl_xor(p2, 1); p3 += __shfl_xor(p3, 1);
    p0 += __shfl_xor(p0, 2); p1 += __shfl_xor(p1, 2);
    p2 += __shfl_xor(p2, 2); p3 += __shfl_xor(p3, 2);
    p0 += __shfl_xor(p0, 4); p1 += __shfl_xor(p1, 4);
    p2 += __shfl_xor(p2, 4); p3 += __shfl_xor(p3, 4);
    p0 = exp2f(p0); p1 = exp2f(p1); p2 = exp2f(p2); p3 = exp2f(p3);
    f32x2 pp0 = {p0, p0}, pp1 = {p1, p1}, pp2 = {p2, p2}, pp3 = {p3, p3};
    sA += p0; a01A = a01A + pp0 * e0a; a23A = a23A + pp0 * e0b;
    sB += p1; a01B = a01B + pp1 * e1a; a23B = a23B + pp1 * e1b;
    sA += p2; a01A = a01A + pp2 * e2a; a23A = a23A + pp2 * e2b;
    sB += p3; a01B = a01B + pp3 * e3a; a23B = a23B + pp3 * e3b;
  }
  for (; i < nedge; ++i) EDGE1((int)csrf[base + (u32)i])

  // overflow fallback (~15 edges total in practice)
  int oc = cnt[NN];
  if (oc > 0) {
    if (oc > OVF_CAP) oc = OVF_CAP;
    for (int k = 0; k < oc; ++k)
      if (ovf[2 * k] == node) EDGE1(ovf[2 * k + 1])
  }

  float inv = 1.f / (sA + sB);
  f32x2 m01 = a01A + a01B, m23 = a23A + a23B;
  uint2 skv = zb2[(u32)node * 128u + 64u + (u32)lane];
  const float4 bv = *(const float4*)(bias + lane * 4);
  float4 o;
  o.x = m01.x * inv + bv.x; o.x = (o.x > 0.f) ? o.x : 0.01f * o.x; o.x += bfl(skv.x);
  o.y = m01.y * inv + bv.y; o.y = (o.y > 0.f) ? o.y : 0.01f * o.y; o.y += bfh(skv.x);
  o.z = m23.x * inv + bv.z; o.z = (o.z > 0.f) ? o.z : 0.01f * o.z; o.z += bfl(skv.y);
  o.w = m23.y * inv + bv.w; o.w = (o.w > 0.f) ? o.w : 0.01f * o.w; o.w += bfh(skv.y);
  *(float4*)(out + (u32)node * 256u + (u32)lane * 4u) = o;
}

extern "C" void kernel_launch(void* const* d_in, const int* in_sizes, int n_in,
                              void* d_out, int out_size, void* d_ws, size_t ws_size,
                              hipStream_t stream) {
  const float* x = (const float*)d_in[0];
  const float* Wl = (const float*)d_in[1];
  const float* Wr = (const float*)d_in[2];
  const float* att = (const float*)d_in[3];
  const float* bias = (const float*)d_in[4];
  const float* Wskip = (const float*)d_in[5];
  const int* ei = (const int*)d_in[6];
  float* out = (float*)d_out;

  char* w = (char*)d_ws;
  size_t off = 0;
  auto alloc = [&](size_t bytes) {
    void* p = w + off;
    off = (off + bytes + 255) & ~(size_t)255;
    return p;
  };
  unsigned short* xb = (unsigned short*)alloc((size_t)NN * 256 * 2);
  unsigned short* wb = (unsigned short*)alloc((size_t)768 * 256 * 2);
  unsigned short* xlb = (unsigned short*)alloc((size_t)NN * 256 * 2);
  unsigned short* zb = (unsigned short*)alloc((size_t)NN * 512 * 2);
  float* av6 = (float*)alloc(256 * 4);
  float* av04 = (float*)alloc(256 * 4);
  int* cnt = (int*)alloc((size_t)(NN + 1) * 4);    // cnt[NN] = overflow counter
  u16* csrf = (u16*)alloc((size_t)NN * CAP * 2);   // 3.2 MB
  int* ovf = (int*)alloc((size_t)OVF_CAP * 2 * 4);
  if (ws_size < off) return;  // clean failure signal (out stays zero)

  hipMemsetAsync(cnt, 0, (size_t)(NN + 1) * 4, stream);
  k_prep<<<SCAT_BLK + 12693, 256, 0, stream>>>((const float4*)x, (const float4*)Wl,
                                               (const float4*)Wr, (const float4*)Wskip,
                                               att, ei, (uint2*)xb, (uint2*)wb,
                                               av6, av04, cnt, csrf, ovf);
  k_gemm<<<NWG, 256, 0, stream>>>(xb, wb, xlb, zb);
  k_agg<<<(NN + 3) / 4, 256, 0, stream>>>((const uint2*)xlb, (const uint2*)zb,
                                          cnt, csrf, ovf, av6, av04, bias, out);
}

// Round 21
// 177.198 us; speedup vs baseline: 1.0722x; 1.0722x over previous
//
#include <hip/hip_runtime.h>

#define NN 50000
#define EE 800000
#define CAP 32          // u16 slots/node -> 3.2 MB csrf
#define OVF_CAP 4096
#define LOG2E 1.44269504088896340736f
#define NWG 2346        // 6 col-panels * 391 row-tiles
#define XQ 293          // NWG/8
#define XR 2            // NWG%8
#define SCAT_BLK 782    // ceil(200000/256); 4 edges/thread

typedef __attribute__((ext_vector_type(4))) float f32x4;
typedef __attribute__((ext_vector_type(8))) short bf16x8;
typedef unsigned int u32;
typedef unsigned short u16;
#define GLOBAL_AS __attribute__((address_space(1)))
#define LDS_AS __attribute__((address_space(3)))

static __device__ __forceinline__ u32 cvtpk_bf16(float lo, float hi) {
  u32 r;
  asm("v_cvt_pk_bf16_f32 %0, %1, %2" : "=v"(r) : "v"(lo), "v"(hi));
  return r;
}
static __device__ __forceinline__ u16 f2bf_hw(float f) {
  return (u16)cvtpk_bf16(f, 0.f);
}
static __device__ __forceinline__ float bfl(unsigned int u) { return __uint_as_float(u << 16); }
static __device__ __forceinline__ float bfh(unsigned int u) { return __uint_as_float(u & 0xFFFF0000u); }

// ---- fused prep: SCATTER FIRST (overlaps conv), then conv x | conv W | att ----
__global__ void k_prep(const float4* __restrict__ x4,
                       const float4* __restrict__ Wl, const float4* __restrict__ Wr,
                       const float4* __restrict__ Ws, const float* __restrict__ att,
                       const int* __restrict__ ei,
                       uint2* __restrict__ xb2, uint2* __restrict__ wb2,
                       float* __restrict__ av6, float* __restrict__ av04,
                       int* __restrict__ cnt, u16* __restrict__ csrf,
                       int* __restrict__ ovf) {
  int b = blockIdx.x;
  if (b < SCAT_BLK) {
    int t = b * 256 + threadIdx.x;
    if (t < EE / 4) {
#pragma unroll
      for (int u = 0; u < 4; ++u) {
        int e = t + u * (EE / 4);
        int dst = ei[EE + e];
        int src = ei[e];
        int slot = atomicAdd(&cnt[dst], 1);
        if (slot < CAP) {
          csrf[dst * CAP + slot] = (u16)src;
        } else {  // guaranteed-correct fallback (~15 edges for Poisson(16))
          int o = atomicAdd(&cnt[NN], 1);  // cnt[NN] = overflow counter
          if (o < OVF_CAP) { ovf[2 * o] = dst; ovf[2 * o + 1] = src; }
        }
      }
    }
  } else if (b < SCAT_BLK + 12500) {
    int i = (b - SCAT_BLK) * 256 + threadIdx.x;  // < 3200000 exactly
    float4 v = x4[i];
    uint2 o;
    o.x = cvtpk_bf16(v.x, v.y);
    o.y = cvtpk_bf16(v.z, v.w);
    xb2[i] = o;
  } else if (b < SCAT_BLK + 12692) {
    int i = (b - SCAT_BLK - 12500) * 256 + threadIdx.x;  // over 49152
    if (i < 49152) {
      int which = i >> 14;
      int idx = i & 16383;
      const float4* W = (which == 0) ? Wl : (which == 1) ? Wr : Ws;
      float4 v = W[idx];
      uint2 o;
      o.x = cvtpk_bf16(v.x, v.y);
      o.y = cvtpk_bf16(v.z, v.w);
      wb2[i] = o;
    }
  } else {
    float a = att[threadIdx.x];
    av6[threadIdx.x] = 0.6f * LOG2E * a;
    av04[threadIdx.x] = 0.4f * LOG2E * a;
  }
}

// ---- GEMM (R10 proven): 32 KB 2-barrier loop, XCD-bijective swizzle,
// LDS-transposed coalesced epilogue, bf16 outputs.
__global__ __launch_bounds__(256) void k_gemm(const unsigned short* __restrict__ xb,
                                              const unsigned short* __restrict__ wb,
                                              unsigned short* __restrict__ xlb,
                                              unsigned short* __restrict__ zb) {
  __shared__ alignas(16) unsigned short Sm[2][128 * 64];
  const int tid = threadIdx.x;
  const int lane = tid & 63;
  const int wave = tid >> 6;
  const int wr = wave >> 1, wc = wave & 1;
  // bijective XCD swizzle (m204): contiguous logical chunk per XCD
  int bid = blockIdx.x;
  int xcd = bid & 7, slot = bid >> 3;
  int wgid = (xcd < XR ? xcd * (XQ + 1) : XR * (XQ + 1) + (xcd - XR) * XQ) + slot;
  const int rbase = (wgid / 6) * 128;
  const int cbase = (wgid % 6) * 128;
  const int rl = lane & 15;
  const int q = lane >> 4;

  f32x4 acc[4][4];
#pragma unroll
  for (int a = 0; a < 4; ++a)
#pragma unroll
    for (int b = 0; b < 4; ++b) acc[a][b] = (f32x4){0.f, 0.f, 0.f, 0.f};

  for (int kt = 0; kt < 256; kt += 64) {
#pragma unroll
    for (int i = 0; i < 4; ++i) {
      int c = tid + i * 256;            // chunk id: 1024 chunks of 16B per buffer
      int row = c >> 3, kcx = c & 7;    // kcx = physical (linear LDS) slot
      int kc = kcx ^ (row & 7);         // logical k-chunk living in slot kcx
      int gr = rbase + row; if (gr > NN - 1) gr = NN - 1;
      int ldsoff = i * 4096 + wave * 1024;  // wave-uniform byte base
      __builtin_amdgcn_global_load_lds(
          (const GLOBAL_AS u32*)(xb + (size_t)gr * 256 + kt + kc * 8),
          (LDS_AS u32*)((LDS_AS char*)&Sm[0][0] + ldsoff), 16, 0, 0);
      __builtin_amdgcn_global_load_lds(
          (const GLOBAL_AS u32*)(wb + (size_t)(cbase + row) * 256 + kt + kc * 8),
          (LDS_AS u32*)((LDS_AS char*)&Sm[1][0] + ldsoff), 16, 0, 0);
    }
    __syncthreads();
#pragma unroll
    for (int ks = 0; ks < 2; ++ks) {
      bf16x8 af[4], bf[4];
      int kc = ks * 4 + q;
#pragma unroll
      for (int t = 0; t < 4; ++t) {
        int ra = wr * 64 + t * 16 + rl;
        af[t] = *(const bf16x8*)((const char*)&Sm[0][0] + ra * 128 + ((kc << 4) ^ ((ra & 7) << 4)));
        int rb = wc * 64 + t * 16 + rl;
        bf[t] = *(const bf16x8*)((const char*)&Sm[1][0] + rb * 128 + ((kc << 4) ^ ((rb & 7) << 4)));
      }
#pragma unroll
      for (int a = 0; a < 4; ++a)
#pragma unroll
        for (int b = 0; b < 4; ++b)
          acc[a][b] = __builtin_amdgcn_mfma_f32_16x16x32_bf16(af[a], bf[b], acc[a][b], 0, 0, 0);
    }
    __syncthreads();
  }
  // ---- epilogue: stage C tile in LDS (swizzled), then coalesced 16B stores ----
  char* Cs = (char*)&Sm[0][0];  // 32 KB = [128 rows][128 cols] bf16, XOR-swizzled
#pragma unroll
  for (int a = 0; a < 4; ++a) {
#pragma unroll
    for (int j = 0; j < 4; ++j) {
      int row = wr * 64 + a * 16 + q * 4 + j;
      int tag = ((row >> 2) & 7) << 5;
#pragma unroll
      for (int b = 0; b < 4; ++b) {
        int col = wc * 64 + b * 16 + rl;
        *(unsigned short*)(Cs + row * 256 + ((col * 2) ^ tag)) = f2bf_hw(acc[a][b][j]);
      }
    }
  }
  __syncthreads();
  const bool isxl = (cbase < 256);
  unsigned short* dst = isxl ? (xlb + cbase) : (zb + (cbase - 256));
  const int dstride = isxl ? 256 : 512;
#pragma unroll
  for (int it = 0; it < 8; ++it) {
    int id = it * 256 + tid;
    int row = id >> 4, cch = id & 15;   // 16 chunks of 8 cols per row
    int tag = ((row >> 2) & 7) << 5;
    uint4 v = *(const uint4*)(Cs + row * 256 + ((cch * 16) ^ tag));
    int grow = rbase + row;
    if (grow < NN)
      *(uint4*)(dst + (size_t)grow * dstride + cch * 8) = v;
  }
}

// ---- per-node FLAT-softmax aggregation (R15 structure, u32 saddr gathers) ----
#define LOGIT6(ex, ey, ez, ew, p)                                      \
  t = ex + xrx; p = a6.x * t;         p = fmaf(a04.x, fabsf(t), p);    \
  t = ey + xry; p = fmaf(a6.y, t, p); p = fmaf(a04.y, fabsf(t), p);    \
  t = ez + xrz; p = fmaf(a6.z, t, p); p = fmaf(a04.z, fabsf(t), p);    \
  t = ew + xrw; p = fmaf(a6.w, t, p); p = fmaf(a04.w, fabsf(t), p);

#define EDGE1(sidx)                                                     \
  {                                                                     \
    uint2 v0 = xl2[(u32)(sidx) * 64u + (u32)lane];                      \
    float e0x = bfl(v0.x), e0y = bfh(v0.x), e0z = bfl(v0.y), e0w = bfh(v0.y); \
    float t, p0;                                                        \
    LOGIT6(e0x, e0y, e0z, e0w, p0)                                      \
    p0 += __shfl_xor(p0, 1);                                            \
    p0 += __shfl_xor(p0, 2);                                            \
    p0 += __shfl_xor(p0, 4);                                            \
    p0 = exp2f(p0);                                                     \
    sA += p0;  axA += p0 * e0x; ayA += p0 * e0y; azA += p0 * e0z; awA += p0 * e0w; \
  }

__global__ __launch_bounds__(256) void k_agg(const uint2* __restrict__ xl2,
                                             const uint2* __restrict__ zb2,
                                             const int* __restrict__ cnt,
                                             const u16* __restrict__ csrf,
                                             const int* __restrict__ ovf,
                                             const float* __restrict__ av6,
                                             const float* __restrict__ av04,
                                             const float* __restrict__ bias,
                                             float* __restrict__ out) {
  int node = blockIdx.x * 4 + (threadIdx.x >> 6);
  if (node >= NN) return;
  int lane = threadIdx.x & 63;

  uint2 xrv = zb2[(u32)node * 128u + (u32)lane];
  float xrx = bfl(xrv.x), xry = bfh(xrv.x), xrz = bfl(xrv.y), xrw = bfh(xrv.y);
  const float4 a6 = *(const float4*)(av6 + lane * 4);
  const float4 a04 = *(const float4*)(av04 + lane * 4);

  float sA = 0.f, axA = 0.f, ayA = 0.f, azA = 0.f, awA = 0.f;
  float sB = 0.f, axB = 0.f, ayB = 0.f, azB = 0.f, awB = 0.f;

  EDGE1(node)  // self-loop

  int nedge = cnt[node];
  if (nedge > CAP) nedge = CAP;
  const u32 base = (u32)node * CAP;
  int i = 0;
  for (; i + 4 <= nedge; i += 4) {
    ushort4 sv = *(const ushort4*)(csrf + base + (u32)i);  // 8B-aligned
    uint2 v0 = xl2[(u32)sv.x * 64u + (u32)lane];
    uint2 v1 = xl2[(u32)sv.y * 64u + (u32)lane];
    uint2 v2 = xl2[(u32)sv.z * 64u + (u32)lane];
    uint2 v3 = xl2[(u32)sv.w * 64u + (u32)lane];
    float e0x = bfl(v0.x), e0y = bfh(v0.x), e0z = bfl(v0.y), e0w = bfh(v0.y);
    float e1x = bfl(v1.x), e1y = bfh(v1.x), e1z = bfl(v1.y), e1w = bfh(v1.y);
    float e2x = bfl(v2.x), e2y = bfh(v2.x), e2z = bfl(v2.y), e2w = bfh(v2.y);
    float e3x = bfl(v3.x), e3y = bfh(v3.x), e3z = bfl(v3.y), e3w = bfh(v3.y);
    float t, p0, p1, p2, p3;
    LOGIT6(e0x, e0y, e0z, e0w, p0)
    LOGIT6(e1x, e1y, e1z, e1w, p1)
    LOGIT6(e2x, e2y, e2z, e2w, p2)
    LOGIT6(e3x, e3y, e3z, e3w, p3)
    p0 += __shfl_xor(p0, 1); p1 += __shfl_xor(p1, 1);
    p2 += __shfl_xor(p2, 1); p3 += __shfl_xor(p3, 1);
    p0 += __shfl_xor(p0, 2); p1 += __shfl_xor(p1, 2);
    p2 += __shfl_xor(p2, 2); p3 += __shfl_xor(p3, 2);
    p0 += __shfl_xor(p0, 4); p1 += __shfl_xor(p1, 4);
    p2 += __shfl_xor(p2, 4); p3 += __shfl_xor(p3, 4);
    p0 = exp2f(p0); p1 = exp2f(p1); p2 = exp2f(p2); p3 = exp2f(p3);
    sA += p0;  axA += p0 * e0x; ayA += p0 * e0y; azA += p0 * e0z; awA += p0 * e0w;
    sB += p1;  axB += p1 * e1x; ayB += p1 * e1y; azB += p1 * e1z; awB += p1 * e1w;
    sA += p2;  axA += p2 * e2x; ayA += p2 * e2y; azA += p2 * e2z; awA += p2 * e2w;
    sB += p3;  axB += p3 * e3x; ayB += p3 * e3y; azB += p3 * e3z; awB += p3 * e3w;
  }
  for (; i < nedge; ++i) EDGE1((int)csrf[base + (u32)i])

  // overflow fallback (~15 edges total in practice)
  int oc = cnt[NN];
  if (oc > 0) {
    if (oc > OVF_CAP) oc = OVF_CAP;
    for (int k = 0; k < oc; ++k)
      if (ovf[2 * k] == node) EDGE1(ovf[2 * k + 1])
  }

  float inv = 1.f / (sA + sB);
  uint2 skv = zb2[(u32)node * 128u + 64u + (u32)lane];
  const float4 bv = *(const float4*)(bias + lane * 4);
  float4 o;
  o.x = (axA + axB) * inv + bv.x; o.x = (o.x > 0.f) ? o.x : 0.01f * o.x; o.x += bfl(skv.x);
  o.y = (ayA + ayB) * inv + bv.y; o.y = (o.y > 0.f) ? o.y : 0.01f * o.y; o.y += bfh(skv.x);
  o.z = (azA + azB) * inv + bv.z; o.z = (o.z > 0.f) ? o.z : 0.01f * o.z; o.z += bfl(skv.y);
  o.w = (awA + awB) * inv + bv.w; o.w = (o.w > 0.f) ? o.w : 0.01f * o.w; o.w += bfh(skv.y);
  *(float4*)(out + (u32)node * 256u + (u32)lane * 4u) = o;
}

extern "C" void kernel_launch(void* const* d_in, const int* in_sizes, int n_in,
                              void* d_out, int out_size, void* d_ws, size_t ws_size,
                              hipStream_t stream) {
  const float* x = (const float*)d_in[0];
  const float* Wl = (const float*)d_in[1];
  const float* Wr = (const float*)d_in[2];
  const float* att = (const float*)d_in[3];
  const float* bias = (const float*)d_in[4];
  const float* Wskip = (const float*)d_in[5];
  const int* ei = (const int*)d_in[6];
  float* out = (float*)d_out;

  char* w = (char*)d_ws;
  size_t off = 0;
  auto alloc = [&](size_t bytes) {
    void* p = w + off;
    off = (off + bytes + 255) & ~(size_t)255;
    return p;
  };
  unsigned short* xb = (unsigned short*)alloc((size_t)NN * 256 * 2);
  unsigned short* wb = (unsigned short*)alloc((size_t)768 * 256 * 2);
  unsigned short* xlb = (unsigned short*)alloc((size_t)NN * 256 * 2);
  unsigned short* zb = (unsigned short*)alloc((size_t)NN * 512 * 2);
  float* av6 = (float*)alloc(256 * 4);
  float* av04 = (float*)alloc(256 * 4);
  int* cnt = (int*)alloc((size_t)(NN + 1) * 4);    // cnt[NN] = overflow counter
  u16* csrf = (u16*)alloc((size_t)NN * CAP * 2);   // 3.2 MB
  int* ovf = (int*)alloc((size_t)OVF_CAP * 2 * 4);
  if (ws_size < off) return;  // clean failure signal (out stays zero)

  hipMemsetAsync(cnt, 0, (size_t)(NN + 1) * 4, stream);
  k_prep<<<SCAT_BLK + 12693, 256, 0, stream>>>((const float4*)x, (const float4*)Wl,
                                               (const float4*)Wr, (const float4*)Wskip,
                                               att, ei, (uint2*)xb, (uint2*)wb,
                                               av6, av04, cnt, csrf, ovf);
  k_gemm<<<NWG, 256, 0, stream>>>(xb, wb, xlb, zb);
  k_agg<<<(NN + 3) / 4, 256, 0, stream>>>((const uint2*)xlb, (const uint2*)zb,
                                          cnt, csrf, ovf, av6, av04, bias, out);
}